// Round 1
// baseline (354.552 us; speedup 1.0000x reference)
//
#include <hip/hip_runtime.h>
#include <stdint.h>
#include <cmath>

typedef short short8 __attribute__((ext_vector_type(8)));
typedef float f32x4 __attribute__((ext_vector_type(4)));

struct ResArr { float r[16]; };

__device__ __forceinline__ uint16_t f2bf(float f) {
  uint32_t u;
  __builtin_memcpy(&u, &f, 4);
  uint32_t r = (u + 0x7FFFu + ((u >> 16) & 1u)) >> 16;  // RNE
  return (uint16_t)r;
}

// ---------------- prep: pack weights into MFMA B-fragment order (bf16) ----
// Fragment order: frag index f = (tile*nS + s); element = [f*64 + lane]*8 + j
// holds W[k = s*32 + (lane>>4)*8 + j][col = tile*16 + (lane&15)].
__global__ __launch_bounds__(256) void prep_pack_kernel(
    const float* __restrict__ W1, const float* __restrict__ W2,
    const float* __restrict__ W3, uint16_t* __restrict__ pW1,
    uint16_t* __restrict__ pW2, uint16_t* __restrict__ pW3) {
  int i = blockIdx.x * 256 + threadIdx.x;
  if (i < 4096) {  // W1 feat part: K=32 (s==0), 8 col-tiles
    int j = i & 7, lane = (i >> 3) & 63, t = i >> 9;
    int k = (lane >> 4) * 8 + j, col = t * 16 + (lane & 15);
    pW1[i] = f2bf(W1[k * 128 + col]);
  } else if (i < 20480) {  // W2: K=128 (4 s-steps), 8 col-tiles
    int q = i - 4096;
    int j = q & 7, lane = (q >> 3) & 63, st = q >> 9;
    int s = st & 3, t = st >> 2;
    int k = s * 32 + (lane >> 4) * 8 + j, col = t * 16 + (lane & 15);
    pW2[q] = f2bf(W2[k * 128 + col]);
  } else if (i < 26624) {  // W3: K=128, 3 col-tiles (42 cols padded to 48)
    int q = i - 20480;
    int j = q & 7, lane = (q >> 3) & 63, st = q >> 9;
    int s = st & 3, t = st >> 2;
    int k = s * 32 + (lane >> 4) * 8 + j, col = t * 16 + (lane & 15);
    pW3[q] = (col < 42) ? f2bf(W3[k * 42 + col]) : (uint16_t)0;
  }
}

// b1' = b1 + cond @ W1[32:160]  (cond constant across points)
__global__ void prep_b1p_kernel(const float* __restrict__ b1,
                                const float* __restrict__ cond,
                                const float* __restrict__ W1,
                                float* __restrict__ b1p) {
  int j = threadIdx.x;  // 128 threads
  float acc = b1[j];
  for (int c = 0; c < 128; ++c) acc += cond[c] * W1[(32 + c) * 128 + j];
  b1p[j] = acc;
}

// ---------------- hash grid encode, level-major for L2 locality ----------
__global__ __launch_bounds__(256) void hash_enc_kernel(
    const float* __restrict__ xyz, const float* __restrict__ amin,
    const float* __restrict__ amax, const float* __restrict__ table,
    uint32_t* __restrict__ featw, int N, int T, ResArr ra) {
  int p = blockIdx.x * 256 + threadIdx.x;
  int lvl = blockIdx.y;
  if (p >= N) return;

  float mn0 = amin[0], mn1 = amin[1], mn2 = amin[2];
  float x = (xyz[p * 3 + 0] - mn0) / (amax[0] - mn0);
  float y = (xyz[p * 3 + 1] - mn1) / (amax[1] - mn1);
  float z = (xyz[p * 3 + 2] - mn2) / (amax[2] - mn2);
  const float hi = 1.0f - 1e-6f;
  x = fminf(fmaxf(x, 0.f), hi);
  y = fminf(fmaxf(y, 0.f), hi);
  z = fminf(fmaxf(z, 0.f), hi);

  float res = ra.r[lvl];
  float xs0 = x * res, xs1 = y * res, xs2 = z * res;
  float c0 = floorf(xs0), c1 = floorf(xs1), c2 = floorf(xs2);
  float fr0 = xs0 - c0, fr1 = xs1 - c1, fr2 = xs2 - c2;
  uint32_t i0 = (uint32_t)(int)c0, i1 = (uint32_t)(int)c1, i2 = (uint32_t)(int)c2;

  uint32_t ax0 = i0, ax1 = i0 + 1u;
  uint32_t ay0 = i1 * 2654435761u, ay1 = (i1 + 1u) * 2654435761u;
  uint32_t az0 = i2 * 805459861u, az1 = (i2 + 1u) * 805459861u;
  uint32_t mask = (uint32_t)(T - 1);
  const float2* tb = (const float2*)table + (size_t)lvl * (size_t)T;

  float wx0 = 1.f - fr0, wy0 = 1.f - fr1, wz0 = 1.f - fr2;
  float a0 = 0.f, a1 = 0.f;
#define CORNER(bx, by, bz)                                              \
  {                                                                     \
    uint32_t h = (bx ? ax1 : ax0) ^ (by ? ay1 : ay0) ^ (bz ? az1 : az0);\
    float2 f = tb[h & mask];                                            \
    float w = (bx ? fr0 : wx0) * (by ? fr1 : wy0) * (bz ? fr2 : wz0);   \
    a0 += w * f.x;                                                      \
    a1 += w * f.y;                                                      \
  }
  CORNER(0, 0, 0) CORNER(0, 0, 1) CORNER(0, 1, 0) CORNER(0, 1, 1)
  CORNER(1, 0, 0) CORNER(1, 0, 1) CORNER(1, 1, 0) CORNER(1, 1, 1)
#undef CORNER
  featw[(size_t)lvl * N + p] = (uint32_t)f2bf(a0) | ((uint32_t)f2bf(a1) << 16);
}

// ---------------- fused MLP (MFMA bf16) + epilogue + loss partials -------
// Block = 256 thr = 4 waves; wave handles 16 points with 16x16x32 MFMA.
__global__ __launch_bounds__(256) void mlp_kernel(
    const uint32_t* __restrict__ featw, const uint16_t* __restrict__ pW1,
    const uint16_t* __restrict__ pW2, const uint16_t* __restrict__ pW3,
    const float* __restrict__ b1p, const float* __restrict__ b2,
    const float* __restrict__ b3, const float* __restrict__ xyz,
    const float* __restrict__ scal, const float* __restrict__ rot,
    float* __restrict__ out, float* __restrict__ partial, int N) {
  // LDS: per-wave h tiles, padded row stride 136 (272B) to dodge bank conflicts
  __shared__ alignas(16) uint16_t h1_lds[4 * 16 * 136];
  __shared__ alignas(16) uint16_t h2_lds[4 * 16 * 136];
  __shared__ float dd[4][16][12];
  __shared__ float bl[4][3];

  int tid = threadIdx.x, wv = tid >> 6, lane = tid & 63;
  int rowi = lane & 15, g = lane >> 4;
  int pbase = blockIdx.x * 64 + wv * 16;
  int prow = pbase + rowi;
  int pc = min(prow, N - 1);

  // ---- layer 1: A = feat (16x32 bf16) straight from global plane layout
  union { uint32_t u[4]; short8 v; } cva;
#pragma unroll
  for (int jj = 0; jj < 4; ++jj)
    cva.u[jj] = featw[(size_t)(g * 4 + jj) * N + pc];
  short8 a1 = cva.v;

  uint16_t* h1w = &h1_lds[wv * 16 * 136];
  const short8* w1f = (const short8*)pW1;
#pragma unroll
  for (int t = 0; t < 8; ++t) {
    float bb = b1p[t * 16 + rowi];
    f32x4 c = {bb, bb, bb, bb};
    c = __builtin_amdgcn_mfma_f32_16x16x32_bf16(a1, w1f[t * 64 + lane], c, 0, 0, 0);
#pragma unroll
    for (int r = 0; r < 4; ++r)  // D: col=lane&15, row=4g+r (HW-verified map)
      h1w[(4 * g + r) * 136 + t * 16 + rowi] = f2bf(fmaxf(c[r], 0.f));
  }
  __syncthreads();

  // ---- layer 2: 128x128
  short8 a2[4];
#pragma unroll
  for (int s = 0; s < 4; ++s)
    a2[s] = *(const short8*)&h1w[rowi * 136 + s * 32 + g * 8];
  const short8* w2f = (const short8*)pW2;
  uint16_t* h2w = &h2_lds[wv * 16 * 136];
#pragma unroll
  for (int t = 0; t < 8; ++t) {
    float bb = b2[t * 16 + rowi];
    f32x4 c = {bb, bb, bb, bb};
#pragma unroll
    for (int s = 0; s < 4; ++s)
      c = __builtin_amdgcn_mfma_f32_16x16x32_bf16(a2[s], w2f[(t * 4 + s) * 64 + lane], c, 0, 0, 0);
#pragma unroll
    for (int r = 0; r < 4; ++r)
      h2w[(4 * g + r) * 136 + t * 16 + rowi] = f2bf(fmaxf(c[r], 0.f));
  }
  __syncthreads();

  // ---- layer 3: 128x48 (42 used)
  short8 a3[4];
#pragma unroll
  for (int s = 0; s < 4; ++s)
    a3[s] = *(const short8*)&h2w[rowi * 136 + s * 32 + g * 8];
  const short8* w3f = (const short8*)pW3;
#pragma unroll
  for (int t = 0; t < 3; ++t) {
    int col = t * 16 + rowi;
    float bb = (col < 42) ? b3[col] : 0.f;
    f32x4 c = {bb, bb, bb, bb};
#pragma unroll
    for (int s = 0; s < 4; ++s)
      c = __builtin_amdgcn_mfma_f32_16x16x32_bf16(a3[s], w3f[(t * 4 + s) * 64 + lane], c, 0, 0, 0);
    if (col >= 10 && col < 42) {  // nr_feat: store directly
#pragma unroll
      for (int r = 0; r < 4; ++r) {
        int p = pbase + 4 * g + r;
        if (p < N) out[(size_t)p * 42 + col] = c[r];
      }
    } else if (col < 10) {  // deltas needing adds/losses -> LDS
#pragma unroll
      for (int r = 0; r < 4; ++r) dd[wv][4 * g + r][col] = c[r];
    }
  }
  __syncthreads();

  // ---- per-point epilogue (lanes 0..15 = one point each)
  float lx = 0.f, ls = 0.f, lr = 0.f;
  if (lane < 16) {
    int p = pbase + lane;
    if (p < N) {
      float d0 = dd[wv][lane][0], d1 = dd[wv][lane][1], d2 = dd[wv][lane][2];
      float d3 = dd[wv][lane][3], d4 = dd[wv][lane][4], d5 = dd[wv][lane][5];
      float d6 = dd[wv][lane][6], d7 = dd[wv][lane][7], d8 = dd[wv][lane][8];
      float d9 = dd[wv][lane][9];
      size_t ob = (size_t)p * 42;
      out[ob + 0] = xyz[p * 3 + 0] + d0;
      out[ob + 1] = xyz[p * 3 + 1] + d1;
      out[ob + 2] = xyz[p * 3 + 2] + d2;
      out[ob + 3] = scal[p * 3 + 0] + d3;
      out[ob + 4] = scal[p * 3 + 1] + d4;
      out[ob + 5] = scal[p * 3 + 2] + d5;
      out[ob + 6] = rot[p * 4 + 0] + d6;
      out[ob + 7] = rot[p * 4 + 1] + d7;
      out[ob + 8] = rot[p * 4 + 2] + d8;
      out[ob + 9] = rot[p * 4 + 3] + d9;
      lx = sqrtf(d0 * d0 + d1 * d1 + d2 * d2);
      ls = fabsf(d3) + fabsf(d4) + fabsf(d5);
      lr = fabsf(d6) + fabsf(d7) + fabsf(d8) + fabsf(d9);
    }
  }
#pragma unroll
  for (int off = 32; off; off >>= 1) {
    lx += __shfl_xor(lx, off);
    ls += __shfl_xor(ls, off);
    lr += __shfl_xor(lr, off);
  }
  if (lane == 0) { bl[wv][0] = lx; bl[wv][1] = ls; bl[wv][2] = lr; }
  __syncthreads();
  if (tid == 0) {
    partial[(size_t)blockIdx.x * 3 + 0] = bl[0][0] + bl[1][0] + bl[2][0] + bl[3][0];
    partial[(size_t)blockIdx.x * 3 + 1] = bl[0][1] + bl[1][1] + bl[2][1] + bl[3][1];
    partial[(size_t)blockIdx.x * 3 + 2] = bl[0][2] + bl[1][2] + bl[2][2] + bl[3][2];
  }
}

// ---------------- finalize: losses row N ---------------------------------
__global__ void finalize_kernel(const float* __restrict__ partial, int nb,
                                float* __restrict__ out, int N) {
  int tid = threadIdx.x, wv = tid >> 6, lane = tid & 63;
  __shared__ float red[4][3];
  float s0 = 0.f, s1 = 0.f, s2 = 0.f;
  for (int i = tid; i < nb; i += 256) {
    s0 += partial[(size_t)i * 3 + 0];
    s1 += partial[(size_t)i * 3 + 1];
    s2 += partial[(size_t)i * 3 + 2];
  }
#pragma unroll
  for (int off = 32; off; off >>= 1) {
    s0 += __shfl_xor(s0, off);
    s1 += __shfl_xor(s1, off);
    s2 += __shfl_xor(s2, off);
  }
  if (lane == 0) { red[wv][0] = s0; red[wv][1] = s1; red[wv][2] = s2; }
  __syncthreads();
  size_t base = (size_t)N * 42;
  if (tid == 0) {
    float t0 = red[0][0] + red[1][0] + red[2][0] + red[3][0];
    float t1 = red[0][1] + red[1][1] + red[2][1] + red[3][1];
    float t2 = red[0][2] + red[1][2] + red[2][2] + red[3][2];
    out[base + 0] = t0 / (float)N;
    out[base + 1] = t1 / (float)N;
    out[base + 2] = t2 / (float)N;
  }
  if (tid >= 3 && tid < 42) out[base + tid] = 0.f;
}

extern "C" void kernel_launch(void* const* d_in, const int* in_sizes, int n_in,
                              void* d_out, int out_size, void* d_ws,
                              size_t ws_size, hipStream_t stream) {
  const float* xyz = (const float*)d_in[0];
  const float* scal = (const float*)d_in[1];
  const float* rot = (const float*)d_in[2];
  const float* cond = (const float*)d_in[3];
  const float* table = (const float*)d_in[4];
  const float* amin = (const float*)d_in[5];
  const float* amax = (const float*)d_in[6];
  const float* W1 = (const float*)d_in[7];
  const float* b1 = (const float*)d_in[8];
  const float* W2 = (const float*)d_in[9];
  const float* b2 = (const float*)d_in[10];
  const float* W3 = (const float*)d_in[11];
  const float* b3 = (const float*)d_in[12];
  float* out = (float*)d_out;

  int N = in_sizes[0] / 3;
  int T = in_sizes[4] / (16 * 2);  // 2^19 entries per level

  // ws layout (all 16B aligned)
  char* ws = (char*)d_ws;
  size_t featB = (size_t)16 * (size_t)N * 4;  // 16 dword planes (2 bf16 each)
  uint32_t* featw = (uint32_t*)ws;
  uint16_t* pW1 = (uint16_t*)(ws + featB);
  uint16_t* pW2 = pW1 + 4096;
  uint16_t* pW3 = pW2 + 16384;
  float* b1p = (float*)(pW3 + 6144);
  float* partial = b1p + 128;

  int nb_mlp = (N + 63) / 64;

  prep_pack_kernel<<<104, 256, 0, stream>>>(W1, W2, W3, pW1, pW2, pW3);
  prep_b1p_kernel<<<1, 128, 0, stream>>>(b1, cond, W1, b1p);

  // per-level resolutions, double precision to match numpy exactly
  ResArr ra;
  double growth = std::pow(2048.0 / 16.0, 1.0 / 15.0);
  for (int l = 0; l < 16; ++l)
    ra.r[l] = (float)std::floor(16.0 * std::pow(growth, (double)l));

  dim3 hg((N + 255) / 256, 16, 1);
  hash_enc_kernel<<<hg, 256, 0, stream>>>(xyz, amin, amax, table, featw, N, T, ra);

  mlp_kernel<<<nb_mlp, 256, 0, stream>>>(featw, pW1, pW2, pW3, b1p, b2, b3,
                                         xyz, scal, rot, out, partial, N);
  finalize_kernel<<<1, 256, 0, stream>>>(partial, nb_mlp, out, N);
}

// Round 2
// 258.699 us; speedup vs baseline: 1.3705x; 1.3705x over previous
//
#include <hip/hip_runtime.h>
#include <stdint.h>
#include <cmath>

typedef short short8 __attribute__((ext_vector_type(8)));
typedef float f32x4 __attribute__((ext_vector_type(4)));

struct ResArr { float r[16]; };

__device__ __forceinline__ uint16_t f2bf(float f) {
  uint32_t u;
  __builtin_memcpy(&u, &f, 4);
  uint32_t r = (u + 0x7FFFu + ((u >> 16) & 1u)) >> 16;  // RNE
  return (uint16_t)r;
}

// ---------------- prep: table f32 -> packed bf16 dwords ------------------
__global__ __launch_bounds__(256) void table_bf16_kernel(
    const float4* __restrict__ t4, uint2* __restrict__ o2, int n4) {
  int i = blockIdx.x * 256 + threadIdx.x;
  int stride = gridDim.x * 256;
  for (; i < n4; i += stride) {
    float4 v = t4[i];
    uint2 o;
    o.x = (uint32_t)f2bf(v.x) | ((uint32_t)f2bf(v.y) << 16);
    o.y = (uint32_t)f2bf(v.z) | ((uint32_t)f2bf(v.w) << 16);
    o2[i] = o;
  }
}

// ---------------- prep: pack weights into MFMA B-fragment order (bf16) ----
__global__ __launch_bounds__(256) void prep_pack_kernel(
    const float* __restrict__ W1, const float* __restrict__ W2,
    const float* __restrict__ W3, uint16_t* __restrict__ pW1,
    uint16_t* __restrict__ pW2, uint16_t* __restrict__ pW3) {
  int i = blockIdx.x * 256 + threadIdx.x;
  if (i < 4096) {  // W1 feat part: K=32 (s==0), 8 col-tiles
    int j = i & 7, lane = (i >> 3) & 63, t = i >> 9;
    int k = (lane >> 4) * 8 + j, col = t * 16 + (lane & 15);
    pW1[i] = f2bf(W1[k * 128 + col]);
  } else if (i < 20480) {  // W2: K=128 (4 s-steps), 8 col-tiles
    int q = i - 4096;
    int j = q & 7, lane = (q >> 3) & 63, st = q >> 9;
    int s = st & 3, t = st >> 2;
    int k = s * 32 + (lane >> 4) * 8 + j, col = t * 16 + (lane & 15);
    pW2[q] = f2bf(W2[k * 128 + col]);
  } else if (i < 26624) {  // W3: K=128, 3 col-tiles (42 cols padded to 48)
    int q = i - 20480;
    int j = q & 7, lane = (q >> 3) & 63, st = q >> 9;
    int s = st & 3, t = st >> 2;
    int k = s * 32 + (lane >> 4) * 8 + j, col = t * 16 + (lane & 15);
    pW3[q] = (col < 42) ? f2bf(W3[k * 42 + col]) : (uint16_t)0;
  }
}

// b1' = b1 + cond @ W1[32:160]  (cond constant across points)
__global__ void prep_b1p_kernel(const float* __restrict__ b1,
                                const float* __restrict__ cond,
                                const float* __restrict__ W1,
                                float* __restrict__ b1p) {
  int j = threadIdx.x;  // 128 threads
  float acc = b1[j];
  for (int c = 0; c < 128; ++c) acc += cond[c] * W1[(32 + c) * 128 + j];
  b1p[j] = acc;
}

// ---------------- hash grid encode, corner-per-lane, level-major ---------
// Wave: 64 lanes. Point math computed point-per-lane (64 pts/wave), then 8
// gather passes of 8 points x 8 corners. x-corner pairs (prime=1) sit in
// adjacent lanes -> same-64B-line coalescing when i0 is even.
template <bool BF>
__global__ __launch_bounds__(256) void hash_enc2_kernel(
    const float* __restrict__ xyz, const float* __restrict__ amin,
    const float* __restrict__ amax, const float* __restrict__ tablef,
    const uint32_t* __restrict__ tableb, uint32_t* __restrict__ featw,
    int N, int T, ResArr ra) {
  int lvl = blockIdx.y;
  int tid = threadIdx.x, wv = tid >> 6, lane = tid & 63, sub = lane & 7;
  int pbase = blockIdx.x * 256 + wv * 64;
  int p = pbase + lane;
  int pc = min(p, N - 1);

  float mn0 = amin[0], mn1 = amin[1], mn2 = amin[2];
  float x = (xyz[pc * 3 + 0] - mn0) / (amax[0] - mn0);
  float y = (xyz[pc * 3 + 1] - mn1) / (amax[1] - mn1);
  float z = (xyz[pc * 3 + 2] - mn2) / (amax[2] - mn2);
  const float hi = 1.0f - 1e-6f;
  x = fminf(fmaxf(x, 0.f), hi);
  y = fminf(fmaxf(y, 0.f), hi);
  z = fminf(fmaxf(z, 0.f), hi);

  float res = ra.r[lvl];
  float xs0 = x * res, xs1 = y * res, xs2 = z * res;
  float c0 = floorf(xs0), c1 = floorf(xs1), c2 = floorf(xs2);
  float fr0 = xs0 - c0, fr1 = xs1 - c1, fr2 = xs2 - c2;
  int i0 = (int)c0, i1 = (int)c1, i2 = (int)c2;

  uint32_t bx = sub & 1, bz = (sub >> 1) & 1, by = (sub >> 2) & 1;
  uint32_t mask = (uint32_t)(T - 1);
  const float2* tbf = (const float2*)tablef + (size_t)lvl * (size_t)T;
  const uint32_t* tbb = tableb + (size_t)lvl * (size_t)T;

#pragma unroll
  for (int g = 0; g < 8; ++g) {
    int src = g * 8 + (lane >> 3);
    uint32_t j0 = (uint32_t)__shfl(i0, src);
    uint32_t j1 = (uint32_t)__shfl(i1, src);
    uint32_t j2 = (uint32_t)__shfl(i2, src);
    float g0 = __shfl(fr0, src), g1 = __shfl(fr1, src), g2 = __shfl(fr2, src);
    uint32_t h = (j0 + bx) ^ ((j1 + by) * 2654435761u) ^ ((j2 + bz) * 805459861u);
    uint32_t idx = h & mask;
    float w = (bx ? g0 : 1.f - g0) * (by ? g1 : 1.f - g1) * (bz ? g2 : 1.f - g2);
    float f0, f1;
    if (BF) {
      uint32_t u = tbb[idx];
      f0 = __uint_as_float(u << 16);
      f1 = __uint_as_float(u & 0xFFFF0000u);
    } else {
      float2 f = tbf[idx];
      f0 = f.x;
      f1 = f.y;
    }
    float v0 = w * f0, v1 = w * f1;
#pragma unroll
    for (int off = 1; off < 8; off <<= 1) {
      v0 += __shfl_xor(v0, off);
      v1 += __shfl_xor(v1, off);
    }
    if (sub == 0) {
      int pw = pbase + g * 8 + (lane >> 3);
      if (pw < N)
        featw[(size_t)lvl * N + pw] =
            (uint32_t)f2bf(v0) | ((uint32_t)f2bf(v1) << 16);
    }
  }
}

// ---------------- fused MLP (MFMA bf16) + epilogue + loss partials -------
__global__ __launch_bounds__(256) void mlp_kernel(
    const uint32_t* __restrict__ featw, const uint16_t* __restrict__ pW1,
    const uint16_t* __restrict__ pW2, const uint16_t* __restrict__ pW3,
    const float* __restrict__ b1p, const float* __restrict__ b2,
    const float* __restrict__ b3, const float* __restrict__ xyz,
    const float* __restrict__ scal, const float* __restrict__ rot,
    float* __restrict__ out, float* __restrict__ partial, int N) {
  __shared__ alignas(16) uint16_t h1_lds[4 * 16 * 136];
  __shared__ alignas(16) uint16_t h2_lds[4 * 16 * 136];
  __shared__ float dd[4][16][12];
  __shared__ float bl[4][3];

  int tid = threadIdx.x, wv = tid >> 6, lane = tid & 63;
  int rowi = lane & 15, g = lane >> 4;
  int pbase = blockIdx.x * 64 + wv * 16;
  int prow = pbase + rowi;
  int pc = min(prow, N - 1);

  union { uint32_t u[4]; short8 v; } cva;
#pragma unroll
  for (int jj = 0; jj < 4; ++jj)
    cva.u[jj] = featw[(size_t)(g * 4 + jj) * N + pc];
  short8 a1 = cva.v;

  uint16_t* h1w = &h1_lds[wv * 16 * 136];
  const short8* w1f = (const short8*)pW1;
#pragma unroll
  for (int t = 0; t < 8; ++t) {
    float bb = b1p[t * 16 + rowi];
    f32x4 c = {bb, bb, bb, bb};
    c = __builtin_amdgcn_mfma_f32_16x16x32_bf16(a1, w1f[t * 64 + lane], c, 0, 0, 0);
#pragma unroll
    for (int r = 0; r < 4; ++r)
      h1w[(4 * g + r) * 136 + t * 16 + rowi] = f2bf(fmaxf(c[r], 0.f));
  }
  __syncthreads();

  short8 a2[4];
#pragma unroll
  for (int s = 0; s < 4; ++s)
    a2[s] = *(const short8*)&h1w[rowi * 136 + s * 32 + g * 8];
  const short8* w2f = (const short8*)pW2;
  uint16_t* h2w = &h2_lds[wv * 16 * 136];
#pragma unroll
  for (int t = 0; t < 8; ++t) {
    float bb = b2[t * 16 + rowi];
    f32x4 c = {bb, bb, bb, bb};
#pragma unroll
    for (int s = 0; s < 4; ++s)
      c = __builtin_amdgcn_mfma_f32_16x16x32_bf16(a2[s], w2f[(t * 4 + s) * 64 + lane], c, 0, 0, 0);
#pragma unroll
    for (int r = 0; r < 4; ++r)
      h2w[(4 * g + r) * 136 + t * 16 + rowi] = f2bf(fmaxf(c[r], 0.f));
  }
  __syncthreads();

  short8 a3[4];
#pragma unroll
  for (int s = 0; s < 4; ++s)
    a3[s] = *(const short8*)&h2w[rowi * 136 + s * 32 + g * 8];
  const short8* w3f = (const short8*)pW3;
#pragma unroll
  for (int t = 0; t < 3; ++t) {
    int col = t * 16 + rowi;
    float bb = (col < 42) ? b3[col] : 0.f;
    f32x4 c = {bb, bb, bb, bb};
#pragma unroll
    for (int s = 0; s < 4; ++s)
      c = __builtin_amdgcn_mfma_f32_16x16x32_bf16(a3[s], w3f[(t * 4 + s) * 64 + lane], c, 0, 0, 0);
    if (col >= 10 && col < 42) {
#pragma unroll
      for (int r = 0; r < 4; ++r) {
        int p = pbase + 4 * g + r;
        if (p < N) out[(size_t)p * 42 + col] = c[r];
      }
    } else if (col < 10) {
#pragma unroll
      for (int r = 0; r < 4; ++r) dd[wv][4 * g + r][col] = c[r];
    }
  }
  __syncthreads();

  float lx = 0.f, ls = 0.f, lr = 0.f;
  if (lane < 16) {
    int p = pbase + lane;
    if (p < N) {
      float d0 = dd[wv][lane][0], d1 = dd[wv][lane][1], d2 = dd[wv][lane][2];
      float d3 = dd[wv][lane][3], d4 = dd[wv][lane][4], d5 = dd[wv][lane][5];
      float d6 = dd[wv][lane][6], d7 = dd[wv][lane][7], d8 = dd[wv][lane][8];
      float d9 = dd[wv][lane][9];
      size_t ob = (size_t)p * 42;
      out[ob + 0] = xyz[p * 3 + 0] + d0;
      out[ob + 1] = xyz[p * 3 + 1] + d1;
      out[ob + 2] = xyz[p * 3 + 2] + d2;
      out[ob + 3] = scal[p * 3 + 0] + d3;
      out[ob + 4] = scal[p * 3 + 1] + d4;
      out[ob + 5] = scal[p * 3 + 2] + d5;
      out[ob + 6] = rot[p * 4 + 0] + d6;
      out[ob + 7] = rot[p * 4 + 1] + d7;
      out[ob + 8] = rot[p * 4 + 2] + d8;
      out[ob + 9] = rot[p * 4 + 3] + d9;
      lx = sqrtf(d0 * d0 + d1 * d1 + d2 * d2);
      ls = fabsf(d3) + fabsf(d4) + fabsf(d5);
      lr = fabsf(d6) + fabsf(d7) + fabsf(d8) + fabsf(d9);
    }
  }
#pragma unroll
  for (int off = 32; off; off >>= 1) {
    lx += __shfl_xor(lx, off);
    ls += __shfl_xor(ls, off);
    lr += __shfl_xor(lr, off);
  }
  if (lane == 0) { bl[wv][0] = lx; bl[wv][1] = ls; bl[wv][2] = lr; }
  __syncthreads();
  if (tid == 0) {
    partial[(size_t)blockIdx.x * 3 + 0] = bl[0][0] + bl[1][0] + bl[2][0] + bl[3][0];
    partial[(size_t)blockIdx.x * 3 + 1] = bl[0][1] + bl[1][1] + bl[2][1] + bl[3][1];
    partial[(size_t)blockIdx.x * 3 + 2] = bl[0][2] + bl[1][2] + bl[2][2] + bl[3][2];
  }
}

// ---------------- finalize: losses row N ---------------------------------
__global__ void finalize_kernel(const float* __restrict__ partial, int nb,
                                float* __restrict__ out, int N) {
  int tid = threadIdx.x, wv = tid >> 6, lane = tid & 63;
  __shared__ float red[4][3];
  float s0 = 0.f, s1 = 0.f, s2 = 0.f;
  for (int i = tid; i < nb; i += 256) {
    s0 += partial[(size_t)i * 3 + 0];
    s1 += partial[(size_t)i * 3 + 1];
    s2 += partial[(size_t)i * 3 + 2];
  }
#pragma unroll
  for (int off = 32; off; off >>= 1) {
    s0 += __shfl_xor(s0, off);
    s1 += __shfl_xor(s1, off);
    s2 += __shfl_xor(s2, off);
  }
  if (lane == 0) { red[wv][0] = s0; red[wv][1] = s1; red[wv][2] = s2; }
  __syncthreads();
  size_t base = (size_t)N * 42;
  if (tid == 0) {
    float t0 = red[0][0] + red[1][0] + red[2][0] + red[3][0];
    float t1 = red[0][1] + red[1][1] + red[2][1] + red[3][1];
    float t2 = red[0][2] + red[1][2] + red[2][2] + red[3][2];
    out[base + 0] = t0 / (float)N;
    out[base + 1] = t1 / (float)N;
    out[base + 2] = t2 / (float)N;
  }
  if (tid >= 3 && tid < 42) out[base + tid] = 0.f;
}

extern "C" void kernel_launch(void* const* d_in, const int* in_sizes, int n_in,
                              void* d_out, int out_size, void* d_ws,
                              size_t ws_size, hipStream_t stream) {
  const float* xyz = (const float*)d_in[0];
  const float* scal = (const float*)d_in[1];
  const float* rot = (const float*)d_in[2];
  const float* cond = (const float*)d_in[3];
  const float* table = (const float*)d_in[4];
  const float* amin = (const float*)d_in[5];
  const float* amax = (const float*)d_in[6];
  const float* W1 = (const float*)d_in[7];
  const float* b1 = (const float*)d_in[8];
  const float* W2 = (const float*)d_in[9];
  const float* b2 = (const float*)d_in[10];
  const float* W3 = (const float*)d_in[11];
  const float* b3 = (const float*)d_in[12];
  float* out = (float*)d_out;

  int N = in_sizes[0] / 3;
  int T = in_sizes[4] / (16 * 2);
  int nb_mlp = (N + 63) / 64;

  // ws layout
  char* ws = (char*)d_ws;
  size_t off = 0;
  size_t featB = (size_t)16 * (size_t)N * 4;
  uint32_t* featw = (uint32_t*)(ws + off); off += featB;
  uint16_t* pW1 = (uint16_t*)(ws + off); off += 4096 * 2;
  uint16_t* pW2 = (uint16_t*)(ws + off); off += 16384 * 2;
  uint16_t* pW3 = (uint16_t*)(ws + off); off += 6144 * 2;
  float* b1p = (float*)(ws + off); off += 128 * 4;
  float* partial = (float*)(ws + off); off += (size_t)nb_mlp * 3 * 4;
  off = (off + 15) & ~(size_t)15;
  uint32_t* tblb = (uint32_t*)(ws + off);
  size_t tblB = (size_t)16 * (size_t)T * 4;
  bool useBF = (ws_size >= off + tblB);

  prep_pack_kernel<<<104, 256, 0, stream>>>(W1, W2, W3, pW1, pW2, pW3);
  prep_b1p_kernel<<<1, 128, 0, stream>>>(b1, cond, W1, b1p);
  if (useBF) {
    int n4 = (int)((size_t)16 * (size_t)T * 2 / 4);  // float4 groups
    table_bf16_kernel<<<2048, 256, 0, stream>>>((const float4*)table,
                                                (uint2*)tblb, n4);
  }

  ResArr ra;
  double growth = std::pow(2048.0 / 16.0, 1.0 / 15.0);
  for (int l = 0; l < 16; ++l)
    ra.r[l] = (float)std::floor(16.0 * std::pow(growth, (double)l));

  dim3 hg((N + 255) / 256, 16, 1);
  if (useBF)
    hash_enc2_kernel<true><<<hg, 256, 0, stream>>>(xyz, amin, amax, table,
                                                   tblb, featw, N, T, ra);
  else
    hash_enc2_kernel<false><<<hg, 256, 0, stream>>>(xyz, amin, amax, table,
                                                    tblb, featw, N, T, ra);

  mlp_kernel<<<nb_mlp, 256, 0, stream>>>(featw, pW1, pW2, pW3, b1p, b2, b3,
                                         xyz, scal, rot, out, partial, N);
  finalize_kernel<<<1, 256, 0, stream>>>(partial, nb_mlp, out, N);
}